// Round 5
// baseline (297.752 us; speedup 1.0000x reference)
//
#include <hip/hip_runtime.h>

// ---------------------------------------------------------------------------
// CavAttention fully fused: B=2 L=5 H=48 W=176 C=256, HEADS=8 DIM=32.
// rows = 84480. R5: block = 40 rows (8 groups of 5), 48-row-PADDED LDS
// buffers -> 72 KB -> 2 BLOCKS/CU. Grid 2112, 512 threads (8 waves, 32
// cols/wave, acc[3][2]). Co-resident independent blocks overlap phases
// (one stages/softmaxes while the other runs MFMA) — attacks the measured
// ~60% all-wave stall of the 1-block/CU serial phase chain (R1-R4).
// Pad rows 40..47 hold garbage; MFMA D-rows depend only on same A-row, and
// pad rows are never read by softmax nor stored. B-operands direct from
// L2-resident bf16 weights. V accs stay in registers through softmax.
// ---------------------------------------------------------------------------

typedef __attribute__((ext_vector_type(8))) short short8;
typedef __attribute__((ext_vector_type(4))) float f32x4;

#define SCALE_F 0.17677669529663687f

static __device__ __forceinline__ float b2f(unsigned short u) {
    union { unsigned u; float f; } x; x.u = ((unsigned)u) << 16; return x.f;
}
static __device__ __forceinline__ unsigned short f2b(float f) {
    union { float f; unsigned u; } x; x.f = f;
    unsigned u = x.u;
    return (unsigned short)((u + 0x7FFFu + ((u >> 16) & 1u)) >> 16);
}

// row r=(b,h,w,l) -> flat element offset in (B,L,H,W,C) order (x and out)
static __device__ __forceinline__ size_t row_to_xoff(int r) {
    int l = r % 5; int t = r / 5;
    int w = t % 176; t /= 176;
    int h = t % 48; int b = t / 48;
    return (size_t)(((b * 5 + l) * 48 + h) * 176 + w) * 256;
}

// swizzled LDS index for [row][256] bf16 buffers: 16B-chunk XOR (row&7)
static __device__ __forceinline__ int lidx(int r, int c) {
    return r * 256 + ((((c >> 3) ^ (r & 7)) << 3) | (c & 7));
}

// lgkmcnt(0)-only barrier: LDS writes visible; global loads stay in flight
static __device__ __forceinline__ void barrier_lgkm() {
    __builtin_amdgcn_s_waitcnt(0xC07F);   // vmcnt=63(free), expcnt=7, lgkmcnt=0
    __builtin_amdgcn_s_barrier();
}

// --------------------------- prep: weights -> bf16, transposed [n][k] ------
// LDS 64x64 tile transpose: coalesced float4 reads, coalesced short8 writes.
__global__ __launch_bounds__(256) void k_prep(const float* __restrict__ wq,
                                              const float* __restrict__ wo,
                                              unsigned short* __restrict__ wqt,
                                              unsigned short* __restrict__ wot) {
    __shared__ unsigned short tile[64 * 65];   // stride 65: gather is conflict-free
    const int bb = blockIdx.x;
    const float* src; unsigned short* dst; int kt, nt, ncols;
    if (bb < 48) { kt = bb / 12; nt = bb % 12; src = wq; dst = wqt; ncols = 768; }
    else { int b2 = bb - 48; kt = b2 >> 2; nt = b2 & 3; src = wo; dst = wot; ncols = 256; }
    const int t = threadIdx.x;
#pragma unroll
    for (int p = 0; p < 4; ++p) {
        int u = p * 256 + t; int r = u >> 4, c4 = u & 15;
        float4 v = *(const float4*)&src[(size_t)(kt * 64 + r) * ncols + nt * 64 + c4 * 4];
        tile[r * 65 + c4 * 4 + 0] = f2b(v.x);
        tile[r * 65 + c4 * 4 + 1] = f2b(v.y);
        tile[r * 65 + c4 * 4 + 2] = f2b(v.z);
        tile[r * 65 + c4 * 4 + 3] = f2b(v.w);
    }
    __syncthreads();
#pragma unroll
    for (int p = 0; p < 2; ++p) {
        int u = p * 256 + t; int n = u >> 3, c8 = u & 7;
        short8 o;
#pragma unroll
        for (int j = 0; j < 8; ++j) o[j] = (short)tile[(c8 * 8 + j) * 65 + n];
        *(short8*)&dst[(nt * 64 + n) * 256 + kt * 64 + c8 * 8] = o;
    }
}

// C/D layout: col = lane&15, row = quad*4 + reg (m89/m91-verified)
static __device__ __forceinline__ void cstore(const f32x4 (&acc)[3][2],
        unsigned short* __restrict__ Ds, int n0w, int lane) {
    const int ln = lane & 15, quad = lane >> 4;
#pragma unroll
    for (int m = 0; m < 3; ++m)
#pragma unroll
        for (int n = 0; n < 2; ++n)
#pragma unroll
            for (int rg = 0; rg < 4; ++rg)
                Ds[lidx(m * 16 + quad * 4 + rg, n0w + n * 16 + ln)] = f2b(acc[m][n][rg]);
}

// --------------------------- the fused kernel ------------------------------
__global__ __launch_bounds__(512, 4) void k_fused(const float* __restrict__ x,
                                                  const int* __restrict__ mask,
                                                  const unsigned short* __restrict__ wqt,
                                                  const unsigned short* __restrict__ wot,
                                                  const float* __restrict__ bo,
                                                  float* __restrict__ out) {
    // 48-row padded buffers: 24 KB each, 72 KB total -> 2 blocks/CU
    __shared__ __align__(16) unsigned short xs[48 * 256];
    __shared__ __align__(16) unsigned short qs[48 * 256];
    __shared__ __align__(16) unsigned short kvs[48 * 256];   // k, then v, then att

    const int tid = threadIdx.x;
    const int blk = blockIdx.x;
    const int rbase = blk * 40;
    const int lane = tid & 63, wv = tid >> 6;   // wv in 0..7
    const int n0w = wv * 32;
    const int ln = lane & 15, quad = lane >> 4;

    // ---- stage x: 40 rows x 256, fp32 -> bf16, swizzled (1280 units/8e) ----
#pragma unroll
    for (int i = 0; i < 3; ++i) {
        int u = i * 512 + tid;
        if (u < 1280) {
            int r = u >> 5, cb = u & 31;
            size_t xo = row_to_xoff(rbase + r) + cb * 8;
            float4 v0 = *(const float4*)(x + xo);
            float4 v1 = *(const float4*)(x + xo + 4);
            short8 o;
            o[0] = (short)f2b(v0.x); o[1] = (short)f2b(v0.y);
            o[2] = (short)f2b(v0.z); o[3] = (short)f2b(v0.w);
            o[4] = (short)f2b(v1.x); o[5] = (short)f2b(v1.y);
            o[6] = (short)f2b(v1.z); o[7] = (short)f2b(v1.w);
            *(short8*)&xs[lidx(r, cb * 8)] = o;
        }
    }

    // ---- mask preload (attention handled by lower 256 threads: 8 grp x 32) --
    const bool act = tid < 256;
    const int part = tid & 3, hh = (tid >> 2) & 7, g = (tid >> 5) & 7;
    int mk[5];
#pragma unroll
    for (int j = 0; j < 5; ++j) mk[j] = act ? mask[(blk * 8 + g) * 5 + j] : 1;

    // per-lane weight base pointers: this lane's B-row, this quad's k-slot
    const unsigned short* wq_l = wqt + (n0w + ln) * 256 + quad * 8;
    const unsigned short* wo_l = wot + (n0w + ln) * 256 + quad * 8;

    barrier_lgkm();   // xs visible

    // ---- Q+K fused gemm: shared A-frags, B direct from global (L2) ----
    f32x4 aq[3][2], ak[3][2];
#pragma unroll
    for (int m = 0; m < 3; ++m)
#pragma unroll
        for (int n = 0; n < 2; ++n) {
            aq[m][n] = (f32x4){0.f, 0.f, 0.f, 0.f};
            ak[m][n] = (f32x4){0.f, 0.f, 0.f, 0.f};
        }
#pragma unroll
    for (int kk = 0; kk < 8; ++kk) {
        short8 a[3];
#pragma unroll
        for (int m = 0; m < 3; ++m)
            a[m] = *(const short8*)&xs[lidx(m * 16 + ln, kk * 32 + quad * 8)];
        short8 bq[2], bk[2];
#pragma unroll
        for (int n = 0; n < 2; ++n) {
            bq[n] = *(const short8*)&wq_l[n * 4096 + kk * 32];            // q rows
            bk[n] = *(const short8*)&wq_l[65536 + n * 4096 + kk * 32];    // k rows
        }
#pragma unroll
        for (int m = 0; m < 3; ++m)
#pragma unroll
            for (int n = 0; n < 2; ++n)
                aq[m][n] = __builtin_amdgcn_mfma_f32_16x16x32_bf16(a[m], bq[n], aq[m][n], 0, 0, 0);
#pragma unroll
        for (int m = 0; m < 3; ++m)
#pragma unroll
            for (int n = 0; n < 2; ++n)
                ak[m][n] = __builtin_amdgcn_mfma_f32_16x16x32_bf16(a[m], bk[n], ak[m][n], 0, 0, 0);
    }
    cstore(aq, qs, n0w, lane);
    cstore(ak, kvs, n0w, lane);

    // ---- V gemm (result stays in registers through softmax) ----
    f32x4 av[3][2];
#pragma unroll
    for (int m = 0; m < 3; ++m)
#pragma unroll
        for (int n = 0; n < 2; ++n) av[m][n] = (f32x4){0.f, 0.f, 0.f, 0.f};
#pragma unroll
    for (int kk = 0; kk < 8; ++kk) {
        short8 a[3];
#pragma unroll
        for (int m = 0; m < 3; ++m)
            a[m] = *(const short8*)&xs[lidx(m * 16 + ln, kk * 32 + quad * 8)];
        short8 bv[2];
#pragma unroll
        for (int n = 0; n < 2; ++n)
            bv[n] = *(const short8*)&wq_l[131072 + n * 4096 + kk * 32];   // v rows
#pragma unroll
        for (int m = 0; m < 3; ++m)
#pragma unroll
            for (int n = 0; n < 2; ++n)
                av[m][n] = __builtin_amdgcn_mfma_f32_16x16x32_bf16(a[m], bv[n], av[m][n], 0, 0, 0);
    }

    barrier_lgkm();   // q,k visible

    // ---- scores + softmax (one group per 32 threads; lower 256) ----
    float pr[5][5];
    if (act) {
        const int c0 = hh * 32 + part * 8;
        float qf[5][8];
#pragma unroll
        for (int i = 0; i < 5; ++i) {
            short8 qv = *(const short8*)&qs[lidx(g * 5 + i, c0)];
#pragma unroll
            for (int d = 0; d < 8; ++d) qf[i][d] = b2f((unsigned short)qv[d]);
        }
        float s[5][5];
#pragma unroll
        for (int j = 0; j < 5; ++j) {
            short8 kv = *(const short8*)&kvs[lidx(g * 5 + j, c0)];
            float kf[8];
#pragma unroll
            for (int d = 0; d < 8; ++d) kf[d] = b2f((unsigned short)kv[d]);
#pragma unroll
            for (int i = 0; i < 5; ++i) {
                float acc = 0.f;
#pragma unroll
                for (int d = 0; d < 8; ++d) acc += qf[i][d] * kf[d];
                s[i][j] = acc;
            }
        }
#pragma unroll
        for (int i = 0; i < 5; ++i)
#pragma unroll
            for (int j = 0; j < 5; ++j) {
                s[i][j] += __shfl_xor(s[i][j], 1, 64);
                s[i][j] += __shfl_xor(s[i][j], 2, 64);
            }
#pragma unroll
        for (int i = 0; i < 5; ++i) {
            float mx = -1e30f;
#pragma unroll
            for (int j = 0; j < 5; ++j) {
                s[i][j] = mk[j] ? s[i][j] * SCALE_F : -1e30f;
                mx = fmaxf(mx, s[i][j]);
            }
            float sum = 0.f;
#pragma unroll
            for (int j = 0; j < 5; ++j) { pr[i][j] = __expf(s[i][j] - mx); sum += pr[i][j]; }
            float inv = 1.f / sum;
#pragma unroll
            for (int j = 0; j < 5; ++j) pr[i][j] *= inv;
        }
    }
    barrier_lgkm();   // all k reads done before v overwrites kvs

    // ---- v store (from registers) ----
    cstore(av, kvs, n0w, lane);
    barrier_lgkm();   // v visible

    // ---- P@V, att written in-place over v (disjoint (row,col) ownership) --
    if (act) {
        const int c0 = hh * 32 + part * 8;
        float o[5][8];
#pragma unroll
        for (int i = 0; i < 5; ++i)
#pragma unroll
            for (int d = 0; d < 8; ++d) o[i][d] = 0.f;
#pragma unroll
        for (int j = 0; j < 5; ++j) {
            short8 vv = *(const short8*)&kvs[lidx(g * 5 + j, c0)];
            float vf[8];
#pragma unroll
            for (int d = 0; d < 8; ++d) vf[d] = b2f((unsigned short)vv[d]);
#pragma unroll
            for (int i = 0; i < 5; ++i)
#pragma unroll
                for (int d = 0; d < 8; ++d) o[i][d] += pr[i][j] * vf[d];
        }
#pragma unroll
        for (int i = 0; i < 5; ++i) {
            short8 ov;
#pragma unroll
            for (int d = 0; d < 8; ++d) ov[d] = (short)f2b(o[i][d]);
            *(short8*)&kvs[lidx(g * 5 + i, c0)] = ov;
        }
    }
    barrier_lgkm();   // att visible

    // ---- out pass: att @ Wout + b -> global fp32 scatter (rows < 40) ----
    {
        f32x4 ao[3][2];
#pragma unroll
        for (int m = 0; m < 3; ++m)
#pragma unroll
            for (int n = 0; n < 2; ++n) ao[m][n] = (f32x4){0.f, 0.f, 0.f, 0.f};
#pragma unroll
        for (int kk = 0; kk < 8; ++kk) {
            short8 a[3];
#pragma unroll
            for (int m = 0; m < 3; ++m)
                a[m] = *(const short8*)&kvs[lidx(m * 16 + ln, kk * 32 + quad * 8)];
            short8 bn[2];
#pragma unroll
            for (int n = 0; n < 2; ++n)
                bn[n] = *(const short8*)&wo_l[n * 4096 + kk * 32];
#pragma unroll
            for (int m = 0; m < 3; ++m)
#pragma unroll
                for (int n = 0; n < 2; ++n)
                    ao[m][n] = __builtin_amdgcn_mfma_f32_16x16x32_bf16(a[m], bn[n], ao[m][n], 0, 0, 0);
        }
        float bv2[2];
#pragma unroll
        for (int n = 0; n < 2; ++n) bv2[n] = bo[n0w + n * 16 + ln];
#pragma unroll
        for (int m = 0; m < 3; ++m)
#pragma unroll
            for (int rg = 0; rg < 4; ++rg) {
                int row = m * 16 + quad * 4 + rg;
                if (row < 40) {
                    size_t off = row_to_xoff(rbase + row);
#pragma unroll
                    for (int n = 0; n < 2; ++n)
                        out[off + n0w + n * 16 + ln] = ao[m][n][rg] + bv2[n];
                }
            }
    }
}

// ---------------------------------------------------------------------------
extern "C" void kernel_launch(void* const* d_in, const int* in_sizes, int n_in,
                              void* d_out, int out_size, void* d_ws, size_t ws_size,
                              hipStream_t stream) {
    const float* x   = (const float*)d_in[0];
    const int* mask  = (const int*)d_in[1];
    const float* wq  = (const float*)d_in[2];
    const float* wo  = (const float*)d_in[3];
    const float* bo  = (const float*)d_in[4];
    float* out = (float*)d_out;

    char* ws = (char*)d_ws;
    // ws: wqt bf16 [768][256] (393216 B) | wot bf16 [256][256] (131072 B)
    unsigned short* wqt = (unsigned short*)(ws);
    unsigned short* wot = (unsigned short*)(ws + 393216);

    hipLaunchKernelGGL(k_prep, dim3(64), dim3(256), 0, stream, wq, wo, wqt, wot);
    hipLaunchKernelGGL(k_fused, dim3(2112), dim3(512), 0, stream, x, mask, wqt, wot, bo, out);
}

// Round 6
// 239.187 us; speedup vs baseline: 1.2448x; 1.2448x over previous
//
#include <hip/hip_runtime.h>

// ---------------------------------------------------------------------------
// CavAttention fully fused: B=2 L=5 H=48 W=176 C=256, HEADS=8 DIM=32.
// rows = 84480. Block = 80 rows (16 groups of 5), 512 threads (8 waves,
// 2/SIMD), grid 1056. R6 = R1 skeleton (best measured: per-wave B-DMA via
// global_load_lds, depth-2, vmcnt(2), lgkm-only barriers) with:
//  - Q/K/V fused into ONE chunk chain (q0,k0,v0,q1,...): A-frags read once
//    per kk (A LDS traffic halved), V accs live in registers thru softmax.
//  - v_cvt_pk_bf16_f32 packed conversions (staging/cstores/PV): ~3x fewer
//    conversion VALU instructions than the scalar round-bit trick.
//  - Continuous chunk chain 0..31: out-pass B prefetched during softmax/PV.
// LDS: xs/qs/kvs 40 KB each + Bb 32 KB = 152 KB, 1 block/CU.
// ---------------------------------------------------------------------------

typedef __attribute__((ext_vector_type(8))) short short8;
typedef __attribute__((ext_vector_type(4))) float f32x4;

#define SCALE_F 0.17677669529663687f

static __device__ __forceinline__ float b2f(unsigned short u) {
    union { unsigned u; float f; } x; x.u = ((unsigned)u) << 16; return x.f;
}
static __device__ __forceinline__ unsigned short f2b(float f) {
    union { float f; unsigned u; } x; x.f = f;
    unsigned u = x.u;
    return (unsigned short)((u + 0x7FFFu + ((u >> 16) & 1u)) >> 16);
}
// packed f32x2 -> bf16x2 (RNE), 1 inst per pair
static __device__ __forceinline__ unsigned pk_bf16(float lo, float hi) {
    unsigned u;
    asm("v_cvt_pk_bf16_f32 %0, %1, %2" : "=v"(u) : "v"(lo), "v"(hi));
    return u;
}

// row r=(b,h,w,l) -> flat element offset in (B,L,H,W,C) order (x and out)
static __device__ __forceinline__ size_t row_to_xoff(int r) {
    int l = r % 5; int t = r / 5;
    int w = t % 176; t /= 176;
    int h = t % 48; int b = t / 48;
    return (size_t)(((b * 5 + l) * 48 + h) * 176 + w) * 256;
}

// swizzled LDS index for [row][256] bf16 buffers: 16B-chunk XOR (row&7)
static __device__ __forceinline__ int lidx(int r, int c) {
    return r * 256 + ((((c >> 3) ^ (r & 7)) << 3) | (c & 7));
}

static __device__ __forceinline__ void async_cp16(const unsigned short* g, unsigned short* l) {
    __builtin_amdgcn_global_load_lds(
        (__attribute__((address_space(1))) void*)(void*)g,
        (__attribute__((address_space(3))) void*)(void*)l, 16, 0, 0);
}

// lgkmcnt(0)-only barrier: LDS writes visible; DMA vmcnt stays in flight
static __device__ __forceinline__ void barrier_lgkm() {
    __builtin_amdgcn_s_waitcnt(0xC07F);   // vmcnt=63(free), expcnt=7, lgkmcnt=0
    __builtin_amdgcn_s_barrier();
}

// --------------------------- prep: weights -> bf16, transposed [n][k] ------
__global__ __launch_bounds__(256) void k_prep(const float* __restrict__ wq,
                                              const float* __restrict__ wo,
                                              unsigned short* __restrict__ wqt,
                                              unsigned short* __restrict__ wot) {
    __shared__ unsigned short tile[64 * 65];
    const int bb = blockIdx.x;
    const float* src; unsigned short* dst; int kt, nt, ncols;
    if (bb < 48) { kt = bb / 12; nt = bb % 12; src = wq; dst = wqt; ncols = 768; }
    else { int b2 = bb - 48; kt = b2 >> 2; nt = b2 & 3; src = wo; dst = wot; ncols = 256; }
    const int t = threadIdx.x;
#pragma unroll
    for (int p = 0; p < 4; ++p) {
        int u = p * 256 + t; int r = u >> 4, c4 = u & 15;
        float4 v = *(const float4*)&src[(size_t)(kt * 64 + r) * ncols + nt * 64 + c4 * 4];
        tile[r * 65 + c4 * 4 + 0] = f2b(v.x);
        tile[r * 65 + c4 * 4 + 1] = f2b(v.y);
        tile[r * 65 + c4 * 4 + 2] = f2b(v.z);
        tile[r * 65 + c4 * 4 + 3] = f2b(v.w);
    }
    __syncthreads();
#pragma unroll
    for (int p = 0; p < 2; ++p) {
        int u = p * 256 + t; int n = u >> 3, c8 = u & 7;
        short8 o;
#pragma unroll
        for (int j = 0; j < 8; ++j) o[j] = (short)tile[(c8 * 8 + j) * 65 + n];
        *(short8*)&dst[(nt * 64 + n) * 256 + kt * 64 + c8 * 8] = o;
    }
}

// ---- chunk map: C 0..23 = {q,k,v} x kk (sel=C%3, kk=C/3); 24..31 = out ----
template<int C>
static __device__ __forceinline__ void issue_chunk(const unsigned short* __restrict__ wqt,
                                                   const unsigned short* __restrict__ wot,
                                                   unsigned short* __restrict__ Bw,
                                                   int n0w, int lane) {
    constexpr int sel = (C < 24) ? (C % 3) : 3;
    constexpr int kk  = (C < 24) ? (C / 3) : (C - 24);
    constexpr int slot = C & 1;
    const unsigned short* wbase = (sel < 3) ? (wqt + sel * 65536) : wot;
#pragma unroll
    for (int t = 0; t < 2; ++t) {
        int cidx = t * 64 + lane;
        int nl = cidx >> 2;                       // B-row within wave chunk (0..31)
        int kq = (cidx & 3) ^ ((nl >> 1) & 3);    // swizzled 16B sub-chunk
        const unsigned short* g = wbase + (n0w + nl) * 256 + kk * 32 + kq * 8;
        async_cp16(g, Bw + slot * 1024 + t * 512);
    }
}

#define MFMA_ALL(ACC)                                                               \
    _Pragma("unroll")                                                               \
    for (int m = 0; m < 5; ++m)                                                     \
        _Pragma("unroll")                                                           \
        for (int n = 0; n < 2; ++n)                                                 \
            ACC[m][n] = __builtin_amdgcn_mfma_f32_16x16x32_bf16(a[m], b[n], ACC[m][n], 0, 0, 0);

// ---- one QKV step: wait chunk C, read B, refill, (a refresh @sel0), 10 MFMA
template<int C>
static __device__ __forceinline__ void qkv_step(f32x4 (&aq)[5][2], f32x4 (&ak)[5][2],
        f32x4 (&av)[5][2], short8 (&a)[5],
        const unsigned short* __restrict__ As, unsigned short* __restrict__ Bw,
        const unsigned short* __restrict__ wqt, const unsigned short* __restrict__ wot,
        int n0w, int lane) {
    constexpr int sel = C % 3;
    constexpr int kk = C / 3;
    constexpr int slot = C & 1;
    const int ln = lane & 15, quad = lane >> 4;
    __builtin_amdgcn_s_waitcnt(0xF72);               // vmcnt(2): chunk C landed
    short8 b[2];
#pragma unroll
    for (int n = 0; n < 2; ++n)
        b[n] = *(const short8*)&Bw[slot * 1024 + (n * 16 + ln) * 32
                                   + ((quad ^ ((ln >> 1) & 3)) * 8)];
    __builtin_amdgcn_s_waitcnt(0xC07F);              // b in VGPRs; slot reusable
    if constexpr (C + 2 < 32) issue_chunk<C + 2>(wqt, wot, Bw, n0w, lane);
    if constexpr (sel == 0) {
#pragma unroll
        for (int m = 0; m < 5; ++m)
            a[m] = *(const short8*)&As[lidx(m * 16 + ln, kk * 32 + quad * 8)];
    }
    if constexpr (sel == 0) { MFMA_ALL(aq) } else if constexpr (sel == 1) { MFMA_ALL(ak) }
    else { MFMA_ALL(av) }
}

// ---- one OUT step (C in 24..31): A from att (kvs) ----
template<int C>
static __device__ __forceinline__ void out_step(f32x4 (&ao)[5][2],
        const unsigned short* __restrict__ As, unsigned short* __restrict__ Bw,
        const unsigned short* __restrict__ wqt, const unsigned short* __restrict__ wot,
        int n0w, int lane) {
    constexpr int kk = C - 24;
    constexpr int slot = C & 1;
    constexpr int imm = (C == 31) ? 0xF70 : 0xF72;   // vmcnt(0) : vmcnt(2)
    const int ln = lane & 15, quad = lane >> 4;
    __builtin_amdgcn_s_waitcnt(imm);
    short8 b[2];
#pragma unroll
    for (int n = 0; n < 2; ++n)
        b[n] = *(const short8*)&Bw[slot * 1024 + (n * 16 + ln) * 32
                                   + ((quad ^ ((ln >> 1) & 3)) * 8)];
    __builtin_amdgcn_s_waitcnt(0xC07F);
    if constexpr (C + 2 < 32) issue_chunk<C + 2>(wqt, wot, Bw, n0w, lane);
    short8 a[5];
#pragma unroll
    for (int m = 0; m < 5; ++m)
        a[m] = *(const short8*)&As[lidx(m * 16 + ln, kk * 32 + quad * 8)];
    MFMA_ALL(ao)
}

// C/D layout: col = lane&15, row = quad*4 + reg; packed-cvt stores
static __device__ __forceinline__ void cstore(const f32x4 (&acc)[5][2],
        unsigned short* __restrict__ Ds, int n0w, int lane) {
    const int ln = lane & 15, quad = lane >> 4;
#pragma unroll
    for (int m = 0; m < 5; ++m)
#pragma unroll
        for (int n = 0; n < 2; ++n) {
            const int col = n0w + n * 16 + ln, r0 = m * 16 + quad * 4;
            unsigned p01 = pk_bf16(acc[m][n][0], acc[m][n][1]);
            unsigned p23 = pk_bf16(acc[m][n][2], acc[m][n][3]);
            Ds[lidx(r0 + 0, col)] = (unsigned short)p01;
            Ds[lidx(r0 + 1, col)] = (unsigned short)(p01 >> 16);
            Ds[lidx(r0 + 2, col)] = (unsigned short)p23;
            Ds[lidx(r0 + 3, col)] = (unsigned short)(p23 >> 16);
        }
}

// --------------------------- the fused kernel ------------------------------
__global__ __launch_bounds__(512, 2) void k_fused(const float* __restrict__ x,
                                                  const int* __restrict__ mask,
                                                  const unsigned short* __restrict__ wqt,
                                                  const unsigned short* __restrict__ wot,
                                                  const float* __restrict__ bo,
                                                  float* __restrict__ out) {
    __shared__ __align__(16) unsigned short xs[80 * 256];    // 40 KB
    __shared__ __align__(16) unsigned short qs[80 * 256];    // 40 KB
    __shared__ __align__(16) unsigned short kvs[80 * 256];   // 40 KB (k, v, att)
    __shared__ __align__(16) unsigned short Bb[8 * 2048];    // 32 KB: 8 waves x 2 slots x 2KB

    const int tid = threadIdx.x;
    const int blk = blockIdx.x;
    const int rbase = blk * 80;
    const int lane = tid & 63, wv = tid >> 6;
    const int n0w = wv * 32;
    const int ln = lane & 15, quad = lane >> 4;
    unsigned short* Bw = Bb + wv * 2048;

    // ---- stage x: 80 rows x 256, fp32 -> bf16 (packed cvt), swizzled ----
#pragma unroll
    for (int i = 0; i < 5; ++i) {
        int u = i * 512 + tid;                    // 2560 units of 8 elems
        int r = u >> 5, cb = u & 31;
        size_t xo = row_to_xoff(rbase + r) + cb * 8;
        float4 v0 = *(const float4*)(x + xo);
        float4 v1 = *(const float4*)(x + xo + 4);
        int4 o;
        o.x = (int)pk_bf16(v0.x, v0.y);
        o.y = (int)pk_bf16(v0.z, v0.w);
        o.z = (int)pk_bf16(v1.x, v1.y);
        o.w = (int)pk_bf16(v1.z, v1.w);
        *(int4*)&xs[lidx(r, cb * 8)] = o;
    }

    // ---- mask preload for this thread's attention group ----
    const int part = tid & 3, hh = (tid >> 2) & 7, g = tid >> 5;  // g in 0..15
    int mk[5];
#pragma unroll
    for (int j = 0; j < 5; ++j) mk[j] = mask[(blk * 16 + g) * 5 + j];

    // prime the B pipeline (wave-private; no barrier needed)
    issue_chunk<0>(wqt, wot, Bw, n0w, lane);
    issue_chunk<1>(wqt, wot, Bw, n0w, lane);

    barrier_lgkm();   // xs visible

    // ---- fused Q/K/V gemm: one chunk chain, A-frags shared across q,k,v ----
    f32x4 aq[5][2], ak[5][2], av[5][2];
#pragma unroll
    for (int m = 0; m < 5; ++m)
#pragma unroll
        for (int n = 0; n < 2; ++n) {
            aq[m][n] = (f32x4){0.f, 0.f, 0.f, 0.f};
            ak[m][n] = (f32x4){0.f, 0.f, 0.f, 0.f};
            av[m][n] = (f32x4){0.f, 0.f, 0.f, 0.f};
        }
    {
        short8 a[5];
        qkv_step<0>(aq, ak, av, a, xs, Bw, wqt, wot, n0w, lane);
        qkv_step<1>(aq, ak, av, a, xs, Bw, wqt, wot, n0w, lane);
        qkv_step<2>(aq, ak, av, a, xs, Bw, wqt, wot, n0w, lane);
        qkv_step<3>(aq, ak, av, a, xs, Bw, wqt, wot, n0w, lane);
        qkv_step<4>(aq, ak, av, a, xs, Bw, wqt, wot, n0w, lane);
        qkv_step<5>(aq, ak, av, a, xs, Bw, wqt, wot, n0w, lane);
        qkv_step<6>(aq, ak, av, a, xs, Bw, wqt, wot, n0w, lane);
        qkv_step<7>(aq, ak, av, a, xs, Bw, wqt, wot, n0w, lane);
        qkv_step<8>(aq, ak, av, a, xs, Bw, wqt, wot, n0w, lane);
        qkv_step<9>(aq, ak, av, a, xs, Bw, wqt, wot, n0w, lane);
        qkv_step<10>(aq, ak, av, a, xs, Bw, wqt, wot, n0w, lane);
        qkv_step<11>(aq, ak, av, a, xs, Bw, wqt, wot, n0w, lane);
        qkv_step<12>(aq, ak, av, a, xs, Bw, wqt, wot, n0w, lane);
        qkv_step<13>(aq, ak, av, a, xs, Bw, wqt, wot, n0w, lane);
        qkv_step<14>(aq, ak, av, a, xs, Bw, wqt, wot, n0w, lane);
        qkv_step<15>(aq, ak, av, a, xs, Bw, wqt, wot, n0w, lane);
        qkv_step<16>(aq, ak, av, a, xs, Bw, wqt, wot, n0w, lane);
        qkv_step<17>(aq, ak, av, a, xs, Bw, wqt, wot, n0w, lane);
        qkv_step<18>(aq, ak, av, a, xs, Bw, wqt, wot, n0w, lane);
        qkv_step<19>(aq, ak, av, a, xs, Bw, wqt, wot, n0w, lane);
        qkv_step<20>(aq, ak, av, a, xs, Bw, wqt, wot, n0w, lane);
        qkv_step<21>(aq, ak, av, a, xs, Bw, wqt, wot, n0w, lane);
        qkv_step<22>(aq, ak, av, a, xs, Bw, wqt, wot, n0w, lane);
        qkv_step<23>(aq, ak, av, a, xs, Bw, wqt, wot, n0w, lane);
    }
    cstore(aq, qs, n0w, lane);
    cstore(ak, kvs, n0w, lane);
    barrier_lgkm();   // q,k visible   (v stays in av registers)

    // ---- scores + softmax (one group per 32 threads) ----
    float pr[5][5];
    {
        const int c0 = hh * 32 + part * 8;
        float qf[5][8];
#pragma unroll
        for (int i = 0; i < 5; ++i) {
            short8 qv = *(const short8*)&qs[lidx(g * 5 + i, c0)];
#pragma unroll
            for (int d = 0; d < 8; ++d) qf[i][d] = b2f((unsigned short)qv[d]);
        }
        float s[5][5];
#pragma unroll
        for (int j = 0; j < 5; ++j) {
            short8 kv = *(const short8*)&kvs[lidx(g * 5 + j, c0)];
            float kf[8];
#pragma unroll
            for (int d = 0; d < 8; ++d) kf[d] = b2f((unsigned short)kv[d]);
#pragma unroll
            for (int i = 0; i < 5; ++i) {
                float acc = 0.f;
#pragma unroll
                for (int d = 0; d < 8; ++d) acc += qf[i][d] * kf[d];
                s[i][j] = acc;
            }
        }
#pragma unroll
        for (int i = 0; i < 5; ++i)
#pragma unroll
            for (int j = 0; j < 5; ++j) {
                s[i][j] += __shfl_xor(s[i][j], 1, 64);
                s[i][j] += __shfl_xor(s[i][j], 2, 64);
            }
#pragma unroll
        for (int i = 0; i < 5; ++i) {
            float mx = -1e30f;
#pragma unroll
            for (int j = 0; j < 5; ++j) {
                s[i][j] = mk[j] ? s[i][j] * SCALE_F : -1e30f;
                mx = fmaxf(mx, s[i][j]);
            }
            float sum = 0.f;
#pragma unroll
            for (int j = 0; j < 5; ++j) { pr[i][j] = __expf(s[i][j] - mx); sum += pr[i][j]; }
            float inv = 1.f / sum;
#pragma unroll
            for (int j = 0; j < 5; ++j) pr[i][j] *= inv;
        }
    }
    barrier_lgkm();   // all k reads done before v overwrites kvs

    // ---- v store (from registers) ----
    cstore(av, kvs, n0w, lane);
    barrier_lgkm();   // v visible

    // ---- P@V, att written in-place over v (disjoint (row,col) ownership) --
    {
        const int c0 = hh * 32 + part * 8;
        float o[5][8];
#pragma unroll
        for (int i = 0; i < 5; ++i)
#pragma unroll
            for (int d = 0; d < 8; ++d) o[i][d] = 0.f;
#pragma unroll
        for (int j = 0; j < 5; ++j) {
            short8 vv = *(const short8*)&kvs[lidx(g * 5 + j, c0)];
            float vf[8];
#pragma unroll
            for (int d = 0; d < 8; ++d) vf[d] = b2f((unsigned short)vv[d]);
#pragma unroll
            for (int i = 0; i < 5; ++i)
#pragma unroll
                for (int d = 0; d < 8; ++d) o[i][d] += pr[i][j] * vf[d];
        }
#pragma unroll
        for (int i = 0; i < 5; ++i) {
            int4 ov;
            ov.x = (int)pk_bf16(o[i][0], o[i][1]);
            ov.y = (int)pk_bf16(o[i][2], o[i][3]);
            ov.z = (int)pk_bf16(o[i][4], o[i][5]);
            ov.w = (int)pk_bf16(o[i][6], o[i][7]);
            *(int4*)&kvs[lidx(g * 5 + i, c0)] = ov;
        }
    }
    barrier_lgkm();   // att visible

    // ---- out pass: att @ Wout + b -> global fp32 scatter ----
    {
        f32x4 ao[5][2];
#pragma unroll
        for (int m = 0; m < 5; ++m)
#pragma unroll
            for (int n = 0; n < 2; ++n) ao[m][n] = (f32x4){0.f, 0.f, 0.f, 0.f};
        out_step<24>(ao, kvs, Bw, wqt, wot, n0w, lane);
        out_step<25>(ao, kvs, Bw, wqt, wot, n0w, lane);
        out_step<26>(ao, kvs, Bw, wqt, wot, n0w, lane);
        out_step<27>(ao, kvs, Bw, wqt, wot, n0w, lane);
        out_step<28>(ao, kvs, Bw, wqt, wot, n0w, lane);
        out_step<29>(ao, kvs, Bw, wqt, wot, n0w, lane);
        out_step<30>(ao, kvs, Bw, wqt, wot, n0w, lane);
        out_step<31>(ao, kvs, Bw, wqt, wot, n0w, lane);
        float bv2[2];
#pragma unroll
        for (int n = 0; n < 2; ++n) bv2[n] = bo[n0w + n * 16 + ln];
#pragma unroll
        for (int m = 0; m < 5; ++m)
#pragma unroll
            for (int rg = 0; rg < 4; ++rg) {
                int row = m * 16 + quad * 4 + rg;
                size_t off = row_to_xoff(rbase + row);
#pragma unroll
                for (int n = 0; n < 2; ++n)
                    out[off + n0w + n * 16 + ln] = ao[m][n][rg] + bv2[n];
            }
    }
}

// ---------------------------------------------------------------------------
extern "C" void kernel_launch(void* const* d_in, const int* in_sizes, int n_in,
                              void* d_out, int out_size, void* d_ws, size_t ws_size,
                              hipStream_t stream) {
    const float* x   = (const float*)d_in[0];
    const int* mask  = (const int*)d_in[1];
    const float* wq  = (const float*)d_in[2];
    const float* wo  = (const float*)d_in[3];
    const float* bo  = (const float*)d_in[4];
    float* out = (float*)d_out;

    char* ws = (char*)d_ws;
    // ws: wqt bf16 [768][256] (393216 B) | wot bf16 [256][256] (131072 B)
    unsigned short* wqt = (unsigned short*)(ws);
    unsigned short* wot = (unsigned short*)(ws + 393216);

    hipLaunchKernelGGL(k_prep, dim3(64), dim3(256), 0, stream, wq, wo, wqt, wot);
    hipLaunchKernelGGL(k_fused, dim3(1056), dim3(512), 0, stream, x, mask, wqt, wot, bo, out);
}